// Round 5
// baseline (216.633 us; speedup 1.0000x reference)
//
#include <hip/hip_runtime.h>

// RelationAwareDiscriminator:
//   out[b,u,v] = sigmoid( sum_{d,e} UE[u,d] * R[r[b],d,e] * VE[v,e] )
// Dedup: out[b] depends on b only via r[b] (64 distinct relations).
// R5: two kernels.
//   K1 computeS: S[rel][u][v] (67 MB, deduped, cached stores) - 512 blocks.
//   K2 copy:     out[b] = S[r[b]] - 4096 uniform 128KB blocks, no barriers,
//                no atomics, NT stores. Pure write-BW stream (like fillBuffer).

#define BATCH 512
#define DIM   128
#define NRELS 64
#define NTHR  256

typedef float floatx4 __attribute__((ext_vector_type(4)));

// ---------------- K1: S[rel][u][v] = sigmoid(UE . R[rel] . VE^T), deduped
__global__ __launch_bounds__(NTHR, 2)
void rad_computeS_kernel(const int* __restrict__ u_idx,
                         const int* __restrict__ v_idx,
                         const float* __restrict__ nodes,   // [100000][128]
                         const float* __restrict__ rels,    // [64][128][128]
                         float* __restrict__ S)             // [64][512][512]
{
    const int rel = (int)blockIdx.x >> 3;          // 0..63
    const int ut0 = ((int)blockIdx.x & 7) * 64;    // 0..448

    __shared__ __align__(16) float s_TsT[DIM * 64];            // [e][u], 32 KB
    __shared__ __align__(16) float s_buf[DIM * 64 + 16 * DIM]; // 40 KB scratch

    const int t  = (int)threadIdx.x;
    const int tu = t >> 4;   // 0..15 (u group of 4)
    const int tx = t & 15;   // 0..15 (e/v group)

    float* UEsT = s_buf;               // [d][u] 128x64, 32 KB
    float* Rs   = s_buf + DIM * 64;    // [dd][e] 16x128, 8 KB

    // Gather u-embedding rows, store transposed [d][u].
    for (int i = t; i < 64 * (DIM / 4); i += NTHR) {
        const int row = i & 63;
        const int dc  = i >> 6; // 0..31
        const float4 val = *reinterpret_cast<const float4*>(
            nodes + (size_t)u_idx[ut0 + row] * DIM + dc * 4);
        UEsT[(dc * 4 + 0) * 64 + row] = val.x;
        UEsT[(dc * 4 + 1) * 64 + row] = val.y;
        UEsT[(dc * 4 + 2) * 64 + row] = val.z;
        UEsT[(dc * 4 + 3) * 64 + row] = val.w;
    }
    __syncthreads();

    // Phase A: TsT[e][u] = sum_d UEsT[d][u] * R[rel][d][e]
    float accA[4][8];
    #pragma unroll
    for (int i = 0; i < 4; ++i)
        #pragma unroll
        for (int j = 0; j < 8; ++j) accA[i][j] = 0.f;

    const float* Rbase = rels + (size_t)rel * DIM * DIM;
    for (int dch = 0; dch < DIM / 16; ++dch) {
        for (int i = t; i < 16 * (DIM / 4); i += NTHR) {
            const int rr = i >> 5;  // 0..15
            const int cc = i & 31;  // 0..31
            *reinterpret_cast<float4*>(Rs + rr * DIM + cc * 4) =
                *reinterpret_cast<const float4*>(
                    Rbase + (size_t)(dch * 16 + rr) * DIM + cc * 4);
        }
        __syncthreads();
        #pragma unroll
        for (int dd = 0; dd < 16; ++dd) {
            const int d = dch * 16 + dd;
            const float4 a  = *reinterpret_cast<const float4*>(UEsT + d * 64 + tu * 4);
            const float4 b0 = *reinterpret_cast<const float4*>(Rs + dd * DIM + tx * 4);
            const float4 b1 = *reinterpret_cast<const float4*>(Rs + dd * DIM + 64 + tx * 4);
            const float av[4] = {a.x, a.y, a.z, a.w};
            const float bv[8] = {b0.x, b0.y, b0.z, b0.w, b1.x, b1.y, b1.z, b1.w};
            #pragma unroll
            for (int i = 0; i < 4; ++i)
                #pragma unroll
                for (int j = 0; j < 8; ++j)
                    accA[i][j] = fmaf(av[i], bv[j], accA[i][j]);
        }
        __syncthreads();
    }

    // Write TsT[e][u].
    #pragma unroll
    for (int j = 0; j < 8; ++j) {
        const int e = (j < 4) ? (tx * 4 + j) : (64 + tx * 4 + (j - 4));
        #pragma unroll
        for (int i = 0; i < 4; ++i)
            s_TsT[e * 64 + tu * 4 + i] = accA[i][j];
    }

    // Phase B: 8 v-chunks; each 64x64 sigmoid tile stored ONCE to S (cached).
    float* VEsT = s_buf; // [e][v] 128x64, reuses scratch
    float* Splane = S + (size_t)rel * BATCH * BATCH;
    for (int vt = 0; vt < BATCH / 64; ++vt) {
        __syncthreads(); // prev chunk's reads done; TsT visible (1st iter)
        for (int i = t; i < 64 * (DIM / 4); i += NTHR) {
            const int row = i & 63;
            const int ec  = i >> 6;
            const float4 val = *reinterpret_cast<const float4*>(
                nodes + (size_t)v_idx[vt * 64 + row] * DIM + ec * 4);
            VEsT[(ec * 4 + 0) * 64 + row] = val.x;
            VEsT[(ec * 4 + 1) * 64 + row] = val.y;
            VEsT[(ec * 4 + 2) * 64 + row] = val.z;
            VEsT[(ec * 4 + 3) * 64 + row] = val.w;
        }
        __syncthreads();

        float acc[4][4];
        #pragma unroll
        for (int i = 0; i < 4; ++i)
            #pragma unroll
            for (int j = 0; j < 4; ++j) acc[i][j] = 0.f;

        #pragma unroll 8
        for (int e = 0; e < DIM; ++e) {
            const float4 a = *reinterpret_cast<const float4*>(s_TsT + e * 64 + tu * 4);
            const float4 b = *reinterpret_cast<const float4*>(VEsT  + e * 64 + tx * 4);
            const float av[4] = {a.x, a.y, a.z, a.w};
            const float bv[4] = {b.x, b.y, b.z, b.w};
            #pragma unroll
            for (int i = 0; i < 4; ++i)
                #pragma unroll
                for (int j = 0; j < 4; ++j)
                    acc[i][j] = fmaf(av[i], bv[j], acc[i][j]);
        }

        #pragma unroll
        for (int i = 0; i < 4; ++i) {
            float4 sg;
            sg.x = 1.f / (1.f + __expf(-acc[i][0]));
            sg.y = 1.f / (1.f + __expf(-acc[i][1]));
            sg.z = 1.f / (1.f + __expf(-acc[i][2]));
            sg.w = 1.f / (1.f + __expf(-acc[i][3]));
            *reinterpret_cast<float4*>(
                Splane + (size_t)(ut0 + tu * 4 + i) * BATCH + vt * 64 + tx * 4) = sg;
        }
    }
}

// ---------------- K2: out[b] = S[r[b]]; 4096 uniform 128KB copy blocks
__global__ __launch_bounds__(NTHR)
void rad_copy_kernel(const int* __restrict__ r_idx,
                     const float* __restrict__ S,   // [64][512][512]
                     float* __restrict__ out)       // [512][512][512]
{
    const int bid   = (int)blockIdx.x;  // 0..4095
    const int b     = bid >> 3;         // 0..511
    const int slice = bid & 7;          // 0..7 (64 rows each)
    const int rel   = r_idx[b];

    const float* src = S   + ((size_t)rel * BATCH + slice * 64) * BATCH;
    float*       dst = out + ((size_t)b   * BATCH + slice * 64) * BATCH;

    // 64 rows x 512 floats = 8192 float4; 256 threads x 32 iters, coalesced.
    const int t = (int)threadIdx.x;
    #pragma unroll 4
    for (int i = t; i < 64 * BATCH / 4; i += NTHR) {
        const floatx4 v = *reinterpret_cast<const floatx4*>(src + i * 4);
        __builtin_nontemporal_store(
            v, reinterpret_cast<floatx4*>(dst + i * 4));
    }
}

// ---------------- Fallback: proven R2 single-kernel (144.5 us) if ws too small
__global__ __launch_bounds__(NTHR, 2)
void rad_fused_kernel(const int* __restrict__ u_idx,
                      const int* __restrict__ v_idx,
                      const int* __restrict__ r_idx,
                      const float* __restrict__ nodes,
                      const float* __restrict__ rels,
                      float* __restrict__ out)
{
    const int rel = (int)blockIdx.x >> 3;
    const int ut0 = ((int)blockIdx.x & 7) * 64;

    __shared__ int s_match[BATCH];
    __shared__ int s_mc;
    __shared__ __align__(16) float s_TsT[DIM * 64];
    __shared__ __align__(16) float s_buf[DIM * 64 + 16 * DIM];

    const int t  = (int)threadIdx.x;
    const int tu = t >> 4;
    const int tx = t & 15;

    if (t == 0) s_mc = 0;
    __syncthreads();
    for (int i = t; i < BATCH; i += NTHR) {
        if (r_idx[i] == rel) {
            int p = atomicAdd(&s_mc, 1);
            s_match[p] = i;
        }
    }

    float* UEsT = s_buf;
    float* Rs   = s_buf + DIM * 64;

    for (int i = t; i < 64 * (DIM / 4); i += NTHR) {
        const int row = i & 63;
        const int dc  = i >> 6;
        const float4 val = *reinterpret_cast<const float4*>(
            nodes + (size_t)u_idx[ut0 + row] * DIM + dc * 4);
        UEsT[(dc * 4 + 0) * 64 + row] = val.x;
        UEsT[(dc * 4 + 1) * 64 + row] = val.y;
        UEsT[(dc * 4 + 2) * 64 + row] = val.z;
        UEsT[(dc * 4 + 3) * 64 + row] = val.w;
    }
    __syncthreads();
    const int mc = s_mc;
    if (mc == 0) return;

    float accA[4][8];
    #pragma unroll
    for (int i = 0; i < 4; ++i)
        #pragma unroll
        for (int j = 0; j < 8; ++j) accA[i][j] = 0.f;

    const float* Rbase = rels + (size_t)rel * DIM * DIM;
    for (int dch = 0; dch < DIM / 16; ++dch) {
        for (int i = t; i < 16 * (DIM / 4); i += NTHR) {
            const int rr = i >> 5;
            const int cc = i & 31;
            *reinterpret_cast<float4*>(Rs + rr * DIM + cc * 4) =
                *reinterpret_cast<const float4*>(
                    Rbase + (size_t)(dch * 16 + rr) * DIM + cc * 4);
        }
        __syncthreads();
        #pragma unroll
        for (int dd = 0; dd < 16; ++dd) {
            const int d = dch * 16 + dd;
            const float4 a  = *reinterpret_cast<const float4*>(UEsT + d * 64 + tu * 4);
            const float4 b0 = *reinterpret_cast<const float4*>(Rs + dd * DIM + tx * 4);
            const float4 b1 = *reinterpret_cast<const float4*>(Rs + dd * DIM + 64 + tx * 4);
            const float av[4] = {a.x, a.y, a.z, a.w};
            const float bv[8] = {b0.x, b0.y, b0.z, b0.w, b1.x, b1.y, b1.z, b1.w};
            #pragma unroll
            for (int i = 0; i < 4; ++i)
                #pragma unroll
                for (int j = 0; j < 8; ++j)
                    accA[i][j] = fmaf(av[i], bv[j], accA[i][j]);
        }
        __syncthreads();
    }

    #pragma unroll
    for (int j = 0; j < 8; ++j) {
        const int e = (j < 4) ? (tx * 4 + j) : (64 + tx * 4 + (j - 4));
        #pragma unroll
        for (int i = 0; i < 4; ++i)
            s_TsT[e * 64 + tu * 4 + i] = accA[i][j];
    }

    float* VEsT = s_buf;
    for (int vt = 0; vt < BATCH / 64; ++vt) {
        __syncthreads();
        for (int i = t; i < 64 * (DIM / 4); i += NTHR) {
            const int row = i & 63;
            const int ec  = i >> 6;
            const float4 val = *reinterpret_cast<const float4*>(
                nodes + (size_t)v_idx[vt * 64 + row] * DIM + ec * 4);
            VEsT[(ec * 4 + 0) * 64 + row] = val.x;
            VEsT[(ec * 4 + 1) * 64 + row] = val.y;
            VEsT[(ec * 4 + 2) * 64 + row] = val.z;
            VEsT[(ec * 4 + 3) * 64 + row] = val.w;
        }
        __syncthreads();

        float acc[4][4];
        #pragma unroll
        for (int i = 0; i < 4; ++i)
            #pragma unroll
            for (int j = 0; j < 4; ++j) acc[i][j] = 0.f;

        #pragma unroll 8
        for (int e = 0; e < DIM; ++e) {
            const float4 a = *reinterpret_cast<const float4*>(s_TsT + e * 64 + tu * 4);
            const float4 b = *reinterpret_cast<const float4*>(VEsT  + e * 64 + tx * 4);
            const float av[4] = {a.x, a.y, a.z, a.w};
            const float bv[4] = {b.x, b.y, b.z, b.w};
            #pragma unroll
            for (int i = 0; i < 4; ++i)
                #pragma unroll
                for (int j = 0; j < 4; ++j)
                    acc[i][j] = fmaf(av[i], bv[j], acc[i][j]);
        }

        floatx4 sg[4];
        #pragma unroll
        for (int i = 0; i < 4; ++i) {
            sg[i].x = 1.f / (1.f + __expf(-acc[i][0]));
            sg[i].y = 1.f / (1.f + __expf(-acc[i][1]));
            sg[i].z = 1.f / (1.f + __expf(-acc[i][2]));
            sg[i].w = 1.f / (1.f + __expf(-acc[i][3]));
        }

        for (int m = 0; m < mc; ++m) {
            const int bb = s_match[m];
            float* obase = out + (size_t)bb * BATCH * BATCH;
            #pragma unroll
            for (int i = 0; i < 4; ++i) {
                floatx4* dst = reinterpret_cast<floatx4*>(
                    obase + (size_t)(ut0 + tu * 4 + i) * BATCH + vt * 64 + tx * 4);
                __builtin_nontemporal_store(sg[i], dst);
            }
        }
    }
}

extern "C" void kernel_launch(void* const* d_in, const int* in_sizes, int n_in,
                              void* d_out, int out_size, void* d_ws, size_t ws_size,
                              hipStream_t stream) {
    const int*   u_idx = (const int*)d_in[0];
    const int*   v_idx = (const int*)d_in[1];
    const int*   r_idx = (const int*)d_in[2];
    const float* nodes = (const float*)d_in[3];
    const float* rels  = (const float*)d_in[4];
    float* out = (float*)d_out;

    const size_t s_bytes = (size_t)NRELS * BATCH * BATCH * sizeof(float); // 67.1 MB
    if (ws_size >= s_bytes) {
        float* S = (float*)d_ws;
        rad_computeS_kernel<<<dim3(NRELS * 8), dim3(NTHR), 0, stream>>>(
            u_idx, v_idx, nodes, rels, S);
        rad_copy_kernel<<<dim3(BATCH * 8), dim3(NTHR), 0, stream>>>(
            r_idx, S, out);
    } else {
        rad_fused_kernel<<<dim3(NRELS * 8), dim3(NTHR), 0, stream>>>(
            u_idx, v_idx, r_idx, nodes, rels, out);
    }
}

// Round 6
// 154.721 us; speedup vs baseline: 1.4002x; 1.4002x over previous
//
#include <hip/hip_runtime.h>

// RelationAwareDiscriminator:
//   out[b,u,v] = sigmoid( sum_{d,e} UE[u,d] * R[r[b],d,e] * VE[v,e] )
// Dedup: out[b] depends on b only via r[b] (64 distinct relations).
// R6: single-pass writes (materialize+copy proven 2x HBM traffic in R5).
//   K1: T[rel][e][u] = (UE.R)^T into ws (16.8 MB) + per-rel match lists.
//   K2: 4096 blocks (rel,ut,vt): one 64x64 tile each, ONE barrier, NT-store
//       mc replicas, exit. No post-store barrier -> no vmcnt(0) serializer;
//       scheduler backfill overlaps next block's staging with store drain.

#define BATCH 512
#define DIM   128
#define NRELS 64
#define NTHR  256

typedef float floatx4 __attribute__((ext_vector_type(4)));

// ws layout
#define T_ELEMS   ((size_t)NRELS * DIM * BATCH)          // [rel][e][u] f32
#define CNT_OFF   (T_ELEMS)                              // 64 ints (as float slots)
#define LIST_OFF  (T_ELEMS + 64)                         // [rel][512] ints
#define WS_NEED   ((T_ELEMS + 64 + (size_t)NRELS * BATCH) * 4)

// ---------------- K1: phase A (T) for bid<512; match lists for bid==512
__global__ __launch_bounds__(NTHR, 2)
void rad_prep_kernel(const int* __restrict__ u_idx,
                     const int* __restrict__ r_idx,
                     const float* __restrict__ nodes,   // [100000][128]
                     const float* __restrict__ rels,    // [64][128][128]
                     float* __restrict__ ws)
{
    const int bid = (int)blockIdx.x;
    const int t   = (int)threadIdx.x;

    if (bid == NRELS * 8) {
        // ---- match-list block
        __shared__ int s_cnt[NRELS];
        int* counts = (int*)(ws + CNT_OFF);
        int* lists  = (int*)(ws + LIST_OFF);
        if (t < NRELS) s_cnt[t] = 0;
        __syncthreads();
        for (int i = t; i < BATCH; i += NTHR) {
            const int rel = r_idx[i];
            const int pos = atomicAdd(&s_cnt[rel], 1);
            lists[rel * BATCH + pos] = i;
        }
        __syncthreads();
        if (t < NRELS) counts[t] = s_cnt[t];
        return;
    }

    // ---- T block: T[rel][e][u] = sum_d UE[u,d] * R[rel][d,e]
    const int rel = bid >> 3;
    const int ut0 = (bid & 7) * 64;

    __shared__ __align__(16) float UEsT[DIM * 64];  // [d][u] 32 KB
    __shared__ __align__(16) float Rs[16 * DIM];    // [dd][e] 8 KB

    const int tu = t >> 4;   // 0..15 (u group of 4)
    const int tx = t & 15;   // 0..15 (e group)

    for (int i = t; i < 64 * (DIM / 4); i += NTHR) {
        const int row = i & 63;
        const int dc  = i >> 6; // 0..31
        const float4 val = *reinterpret_cast<const float4*>(
            nodes + (size_t)u_idx[ut0 + row] * DIM + dc * 4);
        UEsT[(dc * 4 + 0) * 64 + row] = val.x;
        UEsT[(dc * 4 + 1) * 64 + row] = val.y;
        UEsT[(dc * 4 + 2) * 64 + row] = val.z;
        UEsT[(dc * 4 + 3) * 64 + row] = val.w;
    }

    float accA[4][8];
    #pragma unroll
    for (int i = 0; i < 4; ++i)
        #pragma unroll
        for (int j = 0; j < 8; ++j) accA[i][j] = 0.f;

    const float* Rbase = rels + (size_t)rel * DIM * DIM;
    for (int dch = 0; dch < DIM / 16; ++dch) {
        __syncthreads();
        for (int i = t; i < 16 * (DIM / 4); i += NTHR) {
            const int rr = i >> 5;  // 0..15
            const int cc = i & 31;  // 0..31
            *reinterpret_cast<float4*>(Rs + rr * DIM + cc * 4) =
                *reinterpret_cast<const float4*>(
                    Rbase + (size_t)(dch * 16 + rr) * DIM + cc * 4);
        }
        __syncthreads();
        #pragma unroll
        for (int dd = 0; dd < 16; ++dd) {
            const int d = dch * 16 + dd;
            const float4 a  = *reinterpret_cast<const float4*>(UEsT + d * 64 + tu * 4);
            const float4 b0 = *reinterpret_cast<const float4*>(Rs + dd * DIM + tx * 4);
            const float4 b1 = *reinterpret_cast<const float4*>(Rs + dd * DIM + 64 + tx * 4);
            const float av[4] = {a.x, a.y, a.z, a.w};
            const float bv[8] = {b0.x, b0.y, b0.z, b0.w, b1.x, b1.y, b1.z, b1.w};
            #pragma unroll
            for (int i = 0; i < 4; ++i)
                #pragma unroll
                for (int j = 0; j < 8; ++j)
                    accA[i][j] = fmaf(av[i], bv[j], accA[i][j]);
        }
    }

    // Store T[rel][e][ut0 + tu*4 .. +3] as float4 over i (u innermost).
    #pragma unroll
    for (int j = 0; j < 8; ++j) {
        const int e = (j < 4) ? (tx * 4 + j) : (64 + tx * 4 + (j - 4));
        float4 w4 = make_float4(accA[0][j], accA[1][j], accA[2][j], accA[3][j]);
        *reinterpret_cast<float4*>(
            ws + ((size_t)rel * DIM + e) * BATCH + ut0 + tu * 4) = w4;
    }
}

// ---------------- K2: one 64x64 tile per block; NT replica stores; exit.
__global__ __launch_bounds__(NTHR, 2)
void rad_tile_kernel(const int* __restrict__ v_idx,
                     const float* __restrict__ nodes,
                     const float* __restrict__ ws,
                     float* __restrict__ out)       // [512][512][512]
{
    // bid = ((rel*8)+ut)*8 + vt  (vt innermost: siblings dispatch together)
    const int bid = (int)blockIdx.x;
    const int rel = bid >> 6;
    const int ut0 = ((bid >> 3) & 7) * 64;
    const int vt0 = (bid & 7) * 64;

    const int* counts = (const int*)(ws + CNT_OFF);
    const int* lists  = (const int*)(ws + LIST_OFF) + rel * BATCH;
    const int  mc     = counts[rel];
    if (mc == 0) return;

    __shared__ __align__(16) float TsT[DIM * 64];   // [e][u] 32 KB
    __shared__ __align__(16) float VEsT[DIM * 64];  // [e][v] 32 KB

    const int t  = (int)threadIdx.x;
    const int tu = t >> 4;   // 0..15
    const int tx = t & 15;   // 0..15

    // Load T tile: T[rel][e][ut0..ut0+63] -> TsT[e][u], both coalesced.
    const float* Tbase = ws + (size_t)rel * DIM * BATCH + ut0;
    for (int i = t; i < DIM * 16; i += NTHR) {  // 128 e-rows x 16 float4
        const int e  = i >> 4;
        const int uc = i & 15;
        *reinterpret_cast<float4*>(TsT + e * 64 + uc * 4) =
            *reinterpret_cast<const float4*>(Tbase + (size_t)e * BATCH + uc * 4);
    }
    // Gather v-embedding rows transposed [e][v].
    for (int i = t; i < 64 * (DIM / 4); i += NTHR) {
        const int row = i & 63;
        const int ec  = i >> 6;
        const float4 val = *reinterpret_cast<const float4*>(
            nodes + (size_t)v_idx[vt0 + row] * DIM + ec * 4);
        VEsT[(ec * 4 + 0) * 64 + row] = val.x;
        VEsT[(ec * 4 + 1) * 64 + row] = val.y;
        VEsT[(ec * 4 + 2) * 64 + row] = val.z;
        VEsT[(ec * 4 + 3) * 64 + row] = val.w;
    }
    __syncthreads();  // the ONLY barrier in this kernel

    float acc[4][4];
    #pragma unroll
    for (int i = 0; i < 4; ++i)
        #pragma unroll
        for (int j = 0; j < 4; ++j) acc[i][j] = 0.f;

    #pragma unroll 8
    for (int e = 0; e < DIM; ++e) {
        const float4 a = *reinterpret_cast<const float4*>(TsT  + e * 64 + tu * 4);
        const float4 b = *reinterpret_cast<const float4*>(VEsT + e * 64 + tx * 4);
        const float av[4] = {a.x, a.y, a.z, a.w};
        const float bv[4] = {b.x, b.y, b.z, b.w};
        #pragma unroll
        for (int i = 0; i < 4; ++i)
            #pragma unroll
            for (int j = 0; j < 4; ++j)
                acc[i][j] = fmaf(av[i], bv[j], acc[i][j]);
    }

    floatx4 sg[4];
    #pragma unroll
    for (int i = 0; i < 4; ++i) {
        sg[i].x = 1.f / (1.f + __expf(-acc[i][0]));
        sg[i].y = 1.f / (1.f + __expf(-acc[i][1]));
        sg[i].z = 1.f / (1.f + __expf(-acc[i][2]));
        sg[i].w = 1.f / (1.f + __expf(-acc[i][3]));
    }

    // Replicate to every b with r[b]==rel; no barrier after -> wave exits
    // while stores drain; scheduler backfills the CU with the next block.
    for (int m = 0; m < mc; ++m) {
        const int bb = lists[m];
        float* obase = out + (size_t)bb * BATCH * BATCH + vt0 + tx * 4;
        #pragma unroll
        for (int i = 0; i < 4; ++i) {
            __builtin_nontemporal_store(
                sg[i], reinterpret_cast<floatx4*>(
                           obase + (size_t)(ut0 + tu * 4 + i) * BATCH));
        }
    }
}

// ---------------- Fallback: proven R2 single-kernel (144.5 us) if ws too small
__global__ __launch_bounds__(NTHR, 2)
void rad_fused_kernel(const int* __restrict__ u_idx,
                      const int* __restrict__ v_idx,
                      const int* __restrict__ r_idx,
                      const float* __restrict__ nodes,
                      const float* __restrict__ rels,
                      float* __restrict__ out)
{
    const int rel = (int)blockIdx.x >> 3;
    const int ut0 = ((int)blockIdx.x & 7) * 64;

    __shared__ int s_match[BATCH];
    __shared__ int s_mc;
    __shared__ __align__(16) float s_TsT[DIM * 64];
    __shared__ __align__(16) float s_buf[DIM * 64 + 16 * DIM];

    const int t  = (int)threadIdx.x;
    const int tu = t >> 4;
    const int tx = t & 15;

    if (t == 0) s_mc = 0;
    __syncthreads();
    for (int i = t; i < BATCH; i += NTHR) {
        if (r_idx[i] == rel) {
            int p = atomicAdd(&s_mc, 1);
            s_match[p] = i;
        }
    }

    float* UEsT = s_buf;
    float* Rs   = s_buf + DIM * 64;

    for (int i = t; i < 64 * (DIM / 4); i += NTHR) {
        const int row = i & 63;
        const int dc  = i >> 6;
        const float4 val = *reinterpret_cast<const float4*>(
            nodes + (size_t)u_idx[ut0 + row] * DIM + dc * 4);
        UEsT[(dc * 4 + 0) * 64 + row] = val.x;
        UEsT[(dc * 4 + 1) * 64 + row] = val.y;
        UEsT[(dc * 4 + 2) * 64 + row] = val.z;
        UEsT[(dc * 4 + 3) * 64 + row] = val.w;
    }
    __syncthreads();
    const int mc = s_mc;
    if (mc == 0) return;

    float accA[4][8];
    #pragma unroll
    for (int i = 0; i < 4; ++i)
        #pragma unroll
        for (int j = 0; j < 8; ++j) accA[i][j] = 0.f;

    const float* Rbase = rels + (size_t)rel * DIM * DIM;
    for (int dch = 0; dch < DIM / 16; ++dch) {
        for (int i = t; i < 16 * (DIM / 4); i += NTHR) {
            const int rr = i >> 5;
            const int cc = i & 31;
            *reinterpret_cast<float4*>(Rs + rr * DIM + cc * 4) =
                *reinterpret_cast<const float4*>(
                    Rbase + (size_t)(dch * 16 + rr) * DIM + cc * 4);
        }
        __syncthreads();
        #pragma unroll
        for (int dd = 0; dd < 16; ++dd) {
            const int d = dch * 16 + dd;
            const float4 a  = *reinterpret_cast<const float4*>(UEsT + d * 64 + tu * 4);
            const float4 b0 = *reinterpret_cast<const float4*>(Rs + dd * DIM + tx * 4);
            const float4 b1 = *reinterpret_cast<const float4*>(Rs + dd * DIM + 64 + tx * 4);
            const float av[4] = {a.x, a.y, a.z, a.w};
            const float bv[8] = {b0.x, b0.y, b0.z, b0.w, b1.x, b1.y, b1.z, b1.w};
            #pragma unroll
            for (int i = 0; i < 4; ++i)
                #pragma unroll
                for (int j = 0; j < 8; ++j)
                    accA[i][j] = fmaf(av[i], bv[j], accA[i][j]);
        }
        __syncthreads();
    }

    #pragma unroll
    for (int j = 0; j < 8; ++j) {
        const int e = (j < 4) ? (tx * 4 + j) : (64 + tx * 4 + (j - 4));
        #pragma unroll
        for (int i = 0; i < 4; ++i)
            s_TsT[e * 64 + tu * 4 + i] = accA[i][j];
    }

    float* VEsT = s_buf;
    for (int vt = 0; vt < BATCH / 64; ++vt) {
        __syncthreads();
        for (int i = t; i < 64 * (DIM / 4); i += NTHR) {
            const int row = i & 63;
            const int ec  = i >> 6;
            const float4 val = *reinterpret_cast<const float4*>(
                nodes + (size_t)v_idx[vt * 64 + row] * DIM + ec * 4);
            VEsT[(ec * 4 + 0) * 64 + row] = val.x;
            VEsT[(ec * 4 + 1) * 64 + row] = val.y;
            VEsT[(ec * 4 + 2) * 64 + row] = val.z;
            VEsT[(ec * 4 + 3) * 64 + row] = val.w;
        }
        __syncthreads();

        float acc[4][4];
        #pragma unroll
        for (int i = 0; i < 4; ++i)
            #pragma unroll
            for (int j = 0; j < 4; ++j) acc[i][j] = 0.f;

        #pragma unroll 8
        for (int e = 0; e < DIM; ++e) {
            const float4 a = *reinterpret_cast<const float4*>(s_TsT + e * 64 + tu * 4);
            const float4 b = *reinterpret_cast<const float4*>(VEsT  + e * 64 + tx * 4);
            const float av[4] = {a.x, a.y, a.z, a.w};
            const float bv[4] = {b.x, b.y, b.z, b.w};
            #pragma unroll
            for (int i = 0; i < 4; ++i)
                #pragma unroll
                for (int j = 0; j < 4; ++j)
                    acc[i][j] = fmaf(av[i], bv[j], acc[i][j]);
        }

        floatx4 sg[4];
        #pragma unroll
        for (int i = 0; i < 4; ++i) {
            sg[i].x = 1.f / (1.f + __expf(-acc[i][0]));
            sg[i].y = 1.f / (1.f + __expf(-acc[i][1]));
            sg[i].z = 1.f / (1.f + __expf(-acc[i][2]));
            sg[i].w = 1.f / (1.f + __expf(-acc[i][3]));
        }

        for (int m = 0; m < mc; ++m) {
            const int bb = s_match[m];
            float* obase = out + (size_t)bb * BATCH * BATCH;
            #pragma unroll
            for (int i = 0; i < 4; ++i) {
                floatx4* dst = reinterpret_cast<floatx4*>(
                    obase + (size_t)(ut0 + tu * 4 + i) * BATCH + vt * 64 + tx * 4);
                __builtin_nontemporal_store(sg[i], dst);
            }
        }
    }
}

extern "C" void kernel_launch(void* const* d_in, const int* in_sizes, int n_in,
                              void* d_out, int out_size, void* d_ws, size_t ws_size,
                              hipStream_t stream) {
    const int*   u_idx = (const int*)d_in[0];
    const int*   v_idx = (const int*)d_in[1];
    const int*   r_idx = (const int*)d_in[2];
    const float* nodes = (const float*)d_in[3];
    const float* rels  = (const float*)d_in[4];
    float* out = (float*)d_out;

    if (ws_size >= WS_NEED) {
        float* ws = (float*)d_ws;
        rad_prep_kernel<<<dim3(NRELS * 8 + 1), dim3(NTHR), 0, stream>>>(
            u_idx, r_idx, nodes, rels, ws);
        rad_tile_kernel<<<dim3(NRELS * 8 * 8), dim3(NTHR), 0, stream>>>(
            v_idx, nodes, ws, out);
    } else {
        rad_fused_kernel<<<dim3(NRELS * 8), dim3(NTHR), 0, stream>>>(
            u_idx, v_idx, r_idx, nodes, rels, out);
    }
}

// Round 7
// 142.701 us; speedup vs baseline: 1.5181x; 1.0842x over previous
//
#include <hip/hip_runtime.h>

// RelationAwareDiscriminator:
//   out[b,u,v] = sigmoid( sum_{d,e} UE[u,d] * R[r[b],d,e] * VE[v,e] )
// Dedup: out[b] depends on b only via r[b] (64 distinct relations).
// R7: R2's proven single fused kernel +
//   (a) LDS-only barriers in the hot loop (s_waitcnt lgkmcnt(0) + raw
//       s_barrier) so NT-store bursts drain under the NEXT iteration's
//       staging/compute instead of serializing at a vmcnt(0) drain;
//   (b) XCD swizzle: the 8 ut-siblings of each rel land on ONE XCD
//       (bid%8 -> XCD round-robin assumption) so R-matrix + v-row reads
//       hit that XCD's L2 instead of 8x HBM re-fetch.

#define BATCH 512
#define DIM   128
#define NRELS 64
#define NTHR  256

typedef float floatx4 __attribute__((ext_vector_type(4)));

// Barrier that only orders LDS ops: does NOT drain outstanding global
// (NT) stores, unlike __syncthreads() which emits s_waitcnt vmcnt(0).
__device__ __forceinline__ void lds_barrier() {
    asm volatile("s_waitcnt lgkmcnt(0)" ::: "memory");
    __builtin_amdgcn_s_barrier();
    __builtin_amdgcn_sched_barrier(0);
}

__global__ __launch_bounds__(NTHR, 2)
void rad_fused_kernel(const int* __restrict__ u_idx,
                      const int* __restrict__ v_idx,
                      const int* __restrict__ r_idx,
                      const float* __restrict__ nodes,   // [100000][128]
                      const float* __restrict__ rels,    // [64][128][128]
                      float* __restrict__ out)           // [512][512][512]
{
    // XCD-colocating swizzle: blocks with equal bid%8 share an XCD.
    // bid = (rel&7)*64 + ut*8 + (rel>>3)  ->  rel = (bid&7)*8 + (bid>>6),
    // ut = (bid>>3)&7. All 8 ut-siblings of a rel have the same bid%8.
    const int bid = (int)blockIdx.x;
    const int rel = ((bid & 7) << 3) | (bid >> 6);
    const int ut0 = ((bid >> 3) & 7) * 64;

    __shared__ int s_match[BATCH];
    __shared__ int s_mc;
    __shared__ __align__(16) float s_TsT[DIM * 64];            // [e][u], 32 KB
    __shared__ __align__(16) float s_buf[DIM * 64 + 16 * DIM]; // 40 KB scratch

    const int t  = (int)threadIdx.x;
    const int tu = t >> 4;   // 0..15 (u group of 4)
    const int tx = t & 15;   // 0..15 (e/v group)

    if (t == 0) s_mc = 0;
    __syncthreads();
    // Build list of batch indices b with r[b] == rel (order irrelevant).
    for (int i = t; i < BATCH; i += NTHR) {
        if (r_idx[i] == rel) {
            int p = atomicAdd(&s_mc, 1);
            s_match[p] = i;
        }
    }

    float* UEsT = s_buf;               // [d][u] 128x64, 32 KB
    float* Rs   = s_buf + DIM * 64;    // [dd][e] 16x128, 8 KB

    // Gather u-embedding rows, store transposed [d][u].
    for (int i = t; i < 64 * (DIM / 4); i += NTHR) {
        const int row = i & 63;
        const int dc  = i >> 6; // 0..31
        const float4 val = *reinterpret_cast<const float4*>(
            nodes + (size_t)u_idx[ut0 + row] * DIM + dc * 4);
        UEsT[(dc * 4 + 0) * 64 + row] = val.x;
        UEsT[(dc * 4 + 1) * 64 + row] = val.y;
        UEsT[(dc * 4 + 2) * 64 + row] = val.z;
        UEsT[(dc * 4 + 3) * 64 + row] = val.w;
    }
    __syncthreads();
    const int mc = s_mc;
    if (mc == 0) return; // relation absent from batch: nothing to write

    // ---------------- Phase A: TsT[e][u] = sum_d UEsT[d][u] * R[rel][d][e]
    float accA[4][8];
    #pragma unroll
    for (int i = 0; i < 4; ++i)
        #pragma unroll
        for (int j = 0; j < 8; ++j) accA[i][j] = 0.f;

    const float* Rbase = rels + (size_t)rel * DIM * DIM;
    for (int dch = 0; dch < DIM / 16; ++dch) {
        // Stage 16 rows of R into LDS (coalesced float4).
        for (int i = t; i < 16 * (DIM / 4); i += NTHR) {
            const int rr = i >> 5;  // 0..15
            const int cc = i & 31;  // 0..31
            *reinterpret_cast<float4*>(Rs + rr * DIM + cc * 4) =
                *reinterpret_cast<const float4*>(
                    Rbase + (size_t)(dch * 16 + rr) * DIM + cc * 4);
        }
        lds_barrier();
        #pragma unroll
        for (int dd = 0; dd < 16; ++dd) {
            const int d = dch * 16 + dd;
            const float4 a  = *reinterpret_cast<const float4*>(UEsT + d * 64 + tu * 4);
            const float4 b0 = *reinterpret_cast<const float4*>(Rs + dd * DIM + tx * 4);
            const float4 b1 = *reinterpret_cast<const float4*>(Rs + dd * DIM + 64 + tx * 4);
            const float av[4] = {a.x, a.y, a.z, a.w};
            const float bv[8] = {b0.x, b0.y, b0.z, b0.w, b1.x, b1.y, b1.z, b1.w};
            #pragma unroll
            for (int i = 0; i < 4; ++i)
                #pragma unroll
                for (int j = 0; j < 8; ++j)
                    accA[i][j] = fmaf(av[i], bv[j], accA[i][j]);
        }
        lds_barrier();
    }

    // Write TsT[e][u].
    #pragma unroll
    for (int j = 0; j < 8; ++j) {
        const int e = (j < 4) ? (tx * 4 + j) : (64 + tx * 4 + (j - 4));
        #pragma unroll
        for (int i = 0; i < 4; ++i)
            s_TsT[e * 64 + tu * 4 + i] = accA[i][j];
    }

    // ---------------- Phase B: per v-chunk, score tile + sigmoid + replicate
    float* VEsT = s_buf; // [e][v] 128x64, reuses scratch (32 KB)
    for (int vt = 0; vt < BATCH / 64; ++vt) {
        // LDS-only barrier: prev iteration's ds_reads of VEsT are complete
        // (lgkmcnt) in every wave; prior NT stores keep draining unwaited.
        lds_barrier();
        for (int i = t; i < 64 * (DIM / 4); i += NTHR) {
            const int row = i & 63;
            const int ec  = i >> 6;
            const float4 val = *reinterpret_cast<const float4*>(
                nodes + (size_t)v_idx[vt * 64 + row] * DIM + ec * 4);
            VEsT[(ec * 4 + 0) * 64 + row] = val.x;
            VEsT[(ec * 4 + 1) * 64 + row] = val.y;
            VEsT[(ec * 4 + 2) * 64 + row] = val.z;
            VEsT[(ec * 4 + 3) * 64 + row] = val.w;
        }
        lds_barrier();

        float acc[4][4];
        #pragma unroll
        for (int i = 0; i < 4; ++i)
            #pragma unroll
            for (int j = 0; j < 4; ++j) acc[i][j] = 0.f;

        #pragma unroll 8
        for (int e = 0; e < DIM; ++e) {
            const float4 a = *reinterpret_cast<const float4*>(s_TsT + e * 64 + tu * 4);
            const float4 b = *reinterpret_cast<const float4*>(VEsT  + e * 64 + tx * 4);
            const float av[4] = {a.x, a.y, a.z, a.w};
            const float bv[4] = {b.x, b.y, b.z, b.w};
            #pragma unroll
            for (int i = 0; i < 4; ++i)
                #pragma unroll
                for (int j = 0; j < 4; ++j)
                    acc[i][j] = fmaf(av[i], bv[j], acc[i][j]);
        }

        // sigmoid -> native ext_vector for nontemporal stores
        floatx4 sg[4];
        #pragma unroll
        for (int i = 0; i < 4; ++i) {
            sg[i].x = 1.f / (1.f + __expf(-acc[i][0]));
            sg[i].y = 1.f / (1.f + __expf(-acc[i][1]));
            sg[i].z = 1.f / (1.f + __expf(-acc[i][2]));
            sg[i].w = 1.f / (1.f + __expf(-acc[i][3]));
        }

        // Replicate to every b with r[b]==rel. NT stores (protect L2 read
        // lines); no waitcnt after -> they drain under the next iteration.
        for (int m = 0; m < mc; ++m) {
            const int bb = s_match[m];
            float* obase = out + (size_t)bb * BATCH * BATCH + vt * 64 + tx * 4;
            #pragma unroll
            for (int i = 0; i < 4; ++i) {
                __builtin_nontemporal_store(
                    sg[i], reinterpret_cast<floatx4*>(
                               obase + (size_t)(ut0 + tu * 4 + i) * BATCH));
            }
        }
    }
}

extern "C" void kernel_launch(void* const* d_in, const int* in_sizes, int n_in,
                              void* d_out, int out_size, void* d_ws, size_t ws_size,
                              hipStream_t stream) {
    const int*   u_idx = (const int*)d_in[0];
    const int*   v_idx = (const int*)d_in[1];
    const int*   r_idx = (const int*)d_in[2];
    const float* nodes = (const float*)d_in[3];
    const float* rels  = (const float*)d_in[4];
    float* out = (float*)d_out;

    dim3 grid(NRELS * 8); // 512 blocks, XCD-swizzled inside the kernel
    dim3 block(NTHR);
    rad_fused_kernel<<<grid, block, 0, stream>>>(u_idx, v_idx, r_idx, nodes, rels, out);
}